// Round 1
// baseline (1035.973 us; speedup 1.0000x reference)
//
#include <hip/hip_runtime.h>
#include <math.h>

#define N_NODES 100000
#define N_EDGES 3200000
#define IN_DIM 11
#define HID 32
#define HID2 16

// ---------------- degree / norm ----------------
__global__ void k_init_deg(float* __restrict__ deg) {
    int i = blockIdx.x * blockDim.x + threadIdx.x;
    if (i < N_NODES) deg[i] = 1.0f;  // self-loop
}

__global__ void k_count_deg(const int* __restrict__ ei, float* __restrict__ deg) {
    int e = blockIdx.x * blockDim.x + threadIdx.x;
    if (e < N_EDGES) atomicAdd(&deg[ei[N_EDGES + e]], 1.0f);
}

__global__ void k_dinv(float* __restrict__ deg) {
    int i = blockIdx.x * blockDim.x + threadIdx.x;
    if (i < N_NODES) deg[i] = rsqrtf(deg[i]);
}

// ---------------- dense transforms ----------------
// xw = x @ W1   (N x 11) @ (11 x 32); one thread per (node, j)
__global__ void k_xw1(const float* __restrict__ x, const float* __restrict__ W1,
                      float* __restrict__ xw) {
    int t = blockIdx.x * blockDim.x + threadIdx.x;
    if (t >= N_NODES * HID) return;
    int node = t >> 5;
    int j = t & 31;
    float acc = 0.0f;
#pragma unroll
    for (int k = 0; k < IN_DIM; ++k)
        acc += x[node * IN_DIM + k] * W1[k * HID + j];
    xw[t] = acc;
}

// xw = h @ W2   (N x 32) @ (32 x 32); one thread per (node, j)
__global__ void k_xw2(const float* __restrict__ h, const float* __restrict__ W2,
                      float* __restrict__ xw) {
    int t = blockIdx.x * blockDim.x + threadIdx.x;
    if (t >= N_NODES * HID) return;
    int node = t >> 5;
    int j = t & 31;
    __shared__ float sW[HID * HID];
    for (int i = threadIdx.x; i < HID * HID; i += blockDim.x) sW[i] = W2[i];
    __syncthreads();
    if (t >= N_NODES * HID) return;
    float acc = 0.0f;
#pragma unroll
    for (int k = 0; k < HID; ++k)
        acc += h[node * HID + k] * sW[k * HID + j];
    xw[t] = acc;
}

// ---------------- aggregation ----------------
// agg[i][j] = dinv[i]^2 * xw[i][j]   (self-loop term; also initializes agg)
__global__ void k_selfloop(const float* __restrict__ xw, const float* __restrict__ dinv,
                           float* __restrict__ agg) {
    int t = blockIdx.x * blockDim.x + threadIdx.x;
    if (t >= N_NODES * HID) return;
    int node = t >> 5;
    float d = dinv[node];
    agg[t] = d * d * xw[t];
}

// edge scatter: 32 threads per edge, thread j handles feature j
__global__ void k_scatter(const int* __restrict__ ei, const float* __restrict__ dinv,
                          const float* __restrict__ xw, float* __restrict__ agg) {
    int t = blockIdx.x * blockDim.x + threadIdx.x;
    if (t >= N_EDGES * HID) return;
    int e = t >> 5;
    int j = t & 31;
    int s = ei[e];
    int d = ei[N_EDGES + e];
    float norm = dinv[s] * dinv[d];
    atomicAdd(&agg[d * HID + j], norm * xw[s * HID + j]);
}

// h = relu(agg + b)
__global__ void k_bias_relu(const float* __restrict__ agg, const float* __restrict__ b,
                            float* __restrict__ h) {
    int t = blockIdx.x * blockDim.x + threadIdx.x;
    if (t >= N_NODES * HID) return;
    int j = t & 31;
    float v = agg[t] + b[j];
    h[t] = v > 0.0f ? v : 0.0f;
}

// ---------------- output MLP (fused bias2+relu + elu MLP) ----------------
__global__ void k_mlp(const float* __restrict__ agg2, const float* __restrict__ b2,
                      const float* __restrict__ Wo1, const float* __restrict__ bo1,
                      const float* __restrict__ Wo2, const float* __restrict__ bo2,
                      float* __restrict__ out) {
    int node = blockIdx.x * blockDim.x + threadIdx.x;
    __shared__ float sW1[HID * HID2];
    __shared__ float sW2[HID2];
    __shared__ float sb1[HID2];
    for (int i = threadIdx.x; i < HID * HID2; i += blockDim.x) sW1[i] = Wo1[i];
    if (threadIdx.x < HID2) {
        sW2[threadIdx.x] = Wo2[threadIdx.x];
        sb1[threadIdx.x] = bo1[threadIdx.x];
    }
    __syncthreads();
    if (node >= N_NODES) return;
    float h[HID];
#pragma unroll
    for (int k = 0; k < HID; ++k) {
        float v = agg2[node * HID + k] + b2[k];
        h[k] = v > 0.0f ? v : 0.0f;
    }
    float o = bo2[0];
#pragma unroll
    for (int j = 0; j < HID2; ++j) {
        float a = sb1[j];
#pragma unroll
        for (int k = 0; k < HID; ++k) a += h[k] * sW1[k * HID2 + j];
        a = a > 0.0f ? a : (expf(a) - 1.0f);  // elu, alpha=1
        o += a * sW2[j];
    }
    out[node] = o;
}

extern "C" void kernel_launch(void* const* d_in, const int* in_sizes, int n_in,
                              void* d_out, int out_size, void* d_ws, size_t ws_size,
                              hipStream_t stream) {
    const float* x   = (const float*)d_in[0];
    const int*   ei  = (const int*)d_in[1];
    // d_in[2] = batch (unused: single graph, output is per-node)
    const float* W1  = (const float*)d_in[3];
    const float* b1  = (const float*)d_in[4];
    const float* W2  = (const float*)d_in[5];
    const float* b2  = (const float*)d_in[6];
    const float* Wo1 = (const float*)d_in[7];
    const float* bo1 = (const float*)d_in[8];
    const float* Wo2 = (const float*)d_in[9];
    const float* bo2 = (const float*)d_in[10];
    float* out = (float*)d_out;

    // workspace layout (floats): dinv[100352 aligned] | A[N*HID] | B[N*HID]
    float* wsf  = (float*)d_ws;
    float* dinv = wsf;
    float* A    = wsf + 100352;
    float* B    = A + (size_t)N_NODES * HID;

    const int BT = 256;
    int gN   = (N_NODES + BT - 1) / BT;
    int gNH  = (N_NODES * HID + BT - 1) / BT;
    int gE   = (N_EDGES + BT - 1) / BT;
    int gEH  = (int)(((long long)N_EDGES * HID + BT - 1) / BT);

    // norm
    k_init_deg<<<gN, BT, 0, stream>>>(dinv);
    k_count_deg<<<gE, BT, 0, stream>>>(ei, dinv);
    k_dinv<<<gN, BT, 0, stream>>>(dinv);

    // layer 1: A = x@W1 ; B = selfloop + scatter(A) ; A = relu(B + b1)
    k_xw1<<<gNH, BT, 0, stream>>>(x, W1, A);
    k_selfloop<<<gNH, BT, 0, stream>>>(A, dinv, B);
    k_scatter<<<gEH, BT, 0, stream>>>(ei, dinv, A, B);
    k_bias_relu<<<gNH, BT, 0, stream>>>(B, b1, A);

    // layer 2: B = A@W2 ; A = selfloop + scatter(B)
    k_xw2<<<gNH, BT, 0, stream>>>(A, W2, B);
    k_selfloop<<<gNH, BT, 0, stream>>>(B, dinv, A);
    k_scatter<<<gEH, BT, 0, stream>>>(ei, dinv, B, A);

    // head: out = (elu(relu(A+b2)@Wo1 + bo1))@Wo2 + bo2
    k_mlp<<<gN, BT, 0, stream>>>(A, b2, Wo1, bo1, Wo2, bo2, out);
}

// Round 2
// 574.702 us; speedup vs baseline: 1.8026x; 1.8026x over previous
//
#include <hip/hip_runtime.h>
#include <math.h>

#define N_NODES 100000
#define N_EDGES 3200000
#define IN_DIM 11
#define HID 32
#define HID2 16
#define SCHUNK 100352  // per-array stride in ws (multiple of 128 floats)

// ---------------- CSR build ----------------
__global__ void k_zero(int* __restrict__ indeg, int* __restrict__ cursor) {
    int i = blockIdx.x * blockDim.x + threadIdx.x;
    if (i < N_NODES) { indeg[i] = 0; cursor[i] = 0; }
}

__global__ void k_count(const int* __restrict__ ei, int* __restrict__ indeg) {
    int e = blockIdx.x * blockDim.x + threadIdx.x;
    if (e < N_EDGES) atomicAdd(&indeg[ei[N_EDGES + e]], 1);
}

__global__ void k_dinv(const int* __restrict__ indeg, float* __restrict__ dinv) {
    int i = blockIdx.x * blockDim.x + threadIdx.x;
    if (i < N_NODES) dinv[i] = rsqrtf((float)indeg[i] + 1.0f);  // +1 self-loop
}

// exclusive prefix sum, 3 kernels (256-elem blocks -> 391 block sums -> add back)
__global__ void k_scan1(const int* __restrict__ indeg, int* __restrict__ rowstart,
                        int* __restrict__ bsums) {
    __shared__ int tmp[256];
    int gid = blockIdx.x * 256 + threadIdx.x;
    int v = (gid < N_NODES) ? indeg[gid] : 0;
    tmp[threadIdx.x] = v;
    __syncthreads();
    for (int off = 1; off < 256; off <<= 1) {
        int t = (threadIdx.x >= (unsigned)off) ? tmp[threadIdx.x - off] : 0;
        __syncthreads();
        tmp[threadIdx.x] += t;
        __syncthreads();
    }
    if (gid < N_NODES) rowstart[gid] = tmp[threadIdx.x] - v;  // exclusive
    if (threadIdx.x == 255) bsums[blockIdx.x] = tmp[255];
}

__global__ void k_scan2(int* __restrict__ bsums, int nb) {
    __shared__ int tmp[512];
    int v = (threadIdx.x < (unsigned)nb) ? bsums[threadIdx.x] : 0;
    tmp[threadIdx.x] = v;
    __syncthreads();
    for (int off = 1; off < 512; off <<= 1) {
        int t = (threadIdx.x >= (unsigned)off) ? tmp[threadIdx.x - off] : 0;
        __syncthreads();
        tmp[threadIdx.x] += t;
        __syncthreads();
    }
    if (threadIdx.x < (unsigned)nb) bsums[threadIdx.x] = tmp[threadIdx.x] - v;  // exclusive
}

__global__ void k_scan3(int* __restrict__ rowstart, const int* __restrict__ bsums) {
    int gid = blockIdx.x * 256 + threadIdx.x;
    if (gid < N_NODES) rowstart[gid] += bsums[gid >> 8];
    if (gid == 0) rowstart[N_NODES] = N_EDGES;
}

__global__ void k_fill(const int* __restrict__ ei, const int* __restrict__ rowstart,
                       int* __restrict__ cursor, int* __restrict__ csr_src) {
    int e = blockIdx.x * blockDim.x + threadIdx.x;
    if (e >= N_EDGES) return;
    int s = ei[e];
    int d = ei[N_EDGES + e];
    int pos = rowstart[d] + atomicAdd(&cursor[d], 1);
    csr_src[pos] = s;
}

// ---------------- dense transforms ----------------
__global__ void k_xw1(const float* __restrict__ x, const float* __restrict__ W1,
                      float* __restrict__ xw) {
    int t = blockIdx.x * blockDim.x + threadIdx.x;
    if (t >= N_NODES * HID) return;
    int node = t >> 5;
    int j = t & 31;
    float acc = 0.0f;
#pragma unroll
    for (int k = 0; k < IN_DIM; ++k)
        acc += x[node * IN_DIM + k] * W1[k * HID + j];
    xw[t] = acc;
}

__global__ void k_xw2(const float* __restrict__ h, const float* __restrict__ W2,
                      float* __restrict__ xw) {
    int t = blockIdx.x * blockDim.x + threadIdx.x;
    int node = t >> 5;
    int j = t & 31;
    __shared__ float sW[HID * HID];
    for (int i = threadIdx.x; i < HID * HID; i += blockDim.x) sW[i] = W2[i];
    __syncthreads();
    if (t >= N_NODES * HID) return;
    float acc = 0.0f;
#pragma unroll
    for (int k = 0; k < HID; ++k)
        acc += h[node * HID + k] * sW[k * HID + j];
    xw[t] = acc;
}

// ---------------- CSR gather (replaces scatter + selfloop [+ bias/relu]) ----------------
// 32 lanes per node (lane j = feature j); acc = sum_e dinv[src_e] * xw[src_e][j]
// out = dinv[d]*acc + dinv[d]^2*xw[d][j]  (+ bias, relu for layer 1)
__global__ __launch_bounds__(256) void k_gather(const int* __restrict__ rowstart,
                                                const int* __restrict__ csr_src,
                                                const float* __restrict__ dinv,
                                                const float* __restrict__ xw,
                                                const float* __restrict__ bias,
                                                float* __restrict__ outb, int do_relu) {
    int node = blockIdx.x * 8 + (threadIdx.x >> 5);
    int j = threadIdx.x & 31;
    if (node >= N_NODES) return;
    int beg = rowstart[node];
    int end = rowstart[node + 1];
    float acc = 0.0f;
    int e = beg;
    for (; e + 4 <= end; e += 4) {
        int s0 = csr_src[e], s1 = csr_src[e + 1], s2 = csr_src[e + 2], s3 = csr_src[e + 3];
        float d0 = dinv[s0], d1 = dinv[s1], d2 = dinv[s2], d3 = dinv[s3];
        float x0 = xw[s0 * HID + j], x1 = xw[s1 * HID + j];
        float x2 = xw[s2 * HID + j], x3 = xw[s3 * HID + j];
        acc += d0 * x0 + d1 * x1 + d2 * x2 + d3 * x3;
    }
    for (; e < end; ++e) {
        int s = csr_src[e];
        acc += dinv[s] * xw[s * HID + j];
    }
    float dd = dinv[node];
    float v = dd * acc + dd * dd * xw[node * HID + j];
    if (do_relu) {
        v += bias[j];
        v = v > 0.0f ? v : 0.0f;
    }
    outb[node * HID + j] = v;
}

// ---------------- output MLP ----------------
__global__ void k_mlp(const float* __restrict__ agg2, const float* __restrict__ b2,
                      const float* __restrict__ Wo1, const float* __restrict__ bo1,
                      const float* __restrict__ Wo2, const float* __restrict__ bo2,
                      float* __restrict__ out) {
    int node = blockIdx.x * blockDim.x + threadIdx.x;
    __shared__ float sW1[HID * HID2];
    __shared__ float sW2[HID2];
    __shared__ float sb1[HID2];
    for (int i = threadIdx.x; i < HID * HID2; i += blockDim.x) sW1[i] = Wo1[i];
    if (threadIdx.x < HID2) {
        sW2[threadIdx.x] = Wo2[threadIdx.x];
        sb1[threadIdx.x] = bo1[threadIdx.x];
    }
    __syncthreads();
    if (node >= N_NODES) return;
    float h[HID];
#pragma unroll
    for (int k = 0; k < HID; ++k) {
        float v = agg2[node * HID + k] + b2[k];
        h[k] = v > 0.0f ? v : 0.0f;
    }
    float o = bo2[0];
#pragma unroll
    for (int j = 0; j < HID2; ++j) {
        float a = sb1[j];
#pragma unroll
        for (int k = 0; k < HID; ++k) a += h[k] * sW1[k * HID2 + j];
        a = a > 0.0f ? a : (expf(a) - 1.0f);  // elu alpha=1
        o += a * sW2[j];
    }
    out[node] = o;
}

extern "C" void kernel_launch(void* const* d_in, const int* in_sizes, int n_in,
                              void* d_out, int out_size, void* d_ws, size_t ws_size,
                              hipStream_t stream) {
    const float* x   = (const float*)d_in[0];
    const int*   ei  = (const int*)d_in[1];
    const float* W1  = (const float*)d_in[3];
    const float* b1  = (const float*)d_in[4];
    const float* W2  = (const float*)d_in[5];
    const float* b2  = (const float*)d_in[6];
    const float* Wo1 = (const float*)d_in[7];
    const float* bo1 = (const float*)d_in[8];
    const float* Wo2 = (const float*)d_in[9];
    const float* bo2 = (const float*)d_in[10];
    float* out = (float*)d_out;

    // ws layout (4B units): indeg | cursor | dinv | rowstart | bsums | csr_src[E] | A | B
    int*   indeg    = (int*)d_ws;
    int*   cursor   = indeg + SCHUNK;
    float* dinv     = (float*)(cursor + SCHUNK);
    int*   rowstart = (int*)(dinv + SCHUNK);
    int*   bsums    = rowstart + SCHUNK;
    int*   csr_src  = bsums + SCHUNK;
    float* A        = (float*)(csr_src + N_EDGES);
    float* B        = A + (size_t)N_NODES * HID;

    const int BT = 256;
    int gN   = (N_NODES + BT - 1) / BT;             // 391
    int gNH  = (N_NODES * HID + BT - 1) / BT;       // 12500
    int gE   = (N_EDGES + BT - 1) / BT;             // 12500
    int gG   = (N_NODES + 7) / 8;                   // 12500 (8 nodes/block)

    // CSR build + norm
    k_zero <<<gN, BT, 0, stream>>>(indeg, cursor);
    k_count<<<gE, BT, 0, stream>>>(ei, indeg);
    k_dinv <<<gN, BT, 0, stream>>>(indeg, dinv);
    k_scan1<<<gN, BT, 0, stream>>>(indeg, rowstart, bsums);
    k_scan2<<<1, 512, 0, stream>>>(bsums, gN);
    k_scan3<<<gN, BT, 0, stream>>>(rowstart, bsums);
    k_fill <<<gE, BT, 0, stream>>>(ei, rowstart, cursor, csr_src);

    // layer 1: A = x@W1 ; B = gather(A) + bias + relu
    k_xw1<<<gNH, BT, 0, stream>>>(x, W1, A);
    k_gather<<<gG, BT, 0, stream>>>(rowstart, csr_src, dinv, A, b1, B, 1);

    // layer 2: A = B@W2 ; B = gather(A)   (raw agg; bias+relu fused in mlp)
    k_xw2<<<gNH, BT, 0, stream>>>(B, W2, A);
    k_gather<<<gG, BT, 0, stream>>>(rowstart, csr_src, dinv, A, b1, B, 0);

    // head
    k_mlp<<<gN, BT, 0, stream>>>(B, b2, Wo1, bo1, Wo2, bo2, out);
}

// Round 3
// 363.732 us; speedup vs baseline: 2.8482x; 1.5800x over previous
//
#include <hip/hip_runtime.h>
#include <math.h>

#define N_NODES 100000
#define N_EDGES 3200000
#define IN_DIM 11
#define HID 32
#define HID2 16
#define SCHUNK 100352   // per-array stride in ws (multiple of 128)
#define BINSHIFT 8
#define BINSZ 256
#define NB 391          // ceil(100000/256)
#define CHUNK 8192      // edges per block in hist/scatter (391 blocks)

// ---------------- binned CSR build ----------------
__global__ void k_zero_bins(int* __restrict__ bincnt) {
    if (threadIdx.x < NB) bincnt[threadIdx.x] = 0;
}

// per-block LDS histogram of dst bins
__global__ void k_hist(const int* __restrict__ ei, int* __restrict__ bincnt) {
    __shared__ int h[NB];
    for (int i = threadIdx.x; i < NB; i += 256) h[i] = 0;
    __syncthreads();
    int b0 = blockIdx.x * CHUNK;
    int e1 = b0 + CHUNK; if (e1 > N_EDGES) e1 = N_EDGES;
    for (int e = b0 + threadIdx.x; e < e1; e += 256)
        atomicAdd(&h[ei[N_EDGES + e] >> BINSHIFT], 1);
    __syncthreads();
    for (int i = threadIdx.x; i < NB; i += 256)
        if (h[i]) atomicAdd(&bincnt[i], h[i]);
}

// exclusive scan of 391 bin counts (single block)
__global__ void k_scan_bins(const int* __restrict__ bincnt, int* __restrict__ binstart,
                            int* __restrict__ bincur, int* __restrict__ rowstart) {
    __shared__ int tmp[512];
    int v = (threadIdx.x < NB) ? bincnt[threadIdx.x] : 0;
    tmp[threadIdx.x] = v;
    __syncthreads();
    for (int off = 1; off < 512; off <<= 1) {
        int t = (threadIdx.x >= (unsigned)off) ? tmp[threadIdx.x - off] : 0;
        __syncthreads();
        tmp[threadIdx.x] += t;
        __syncthreads();
    }
    if (threadIdx.x < NB) {
        int ex = tmp[threadIdx.x] - v;
        binstart[threadIdx.x] = ex;
        bincur[threadIdx.x] = ex;
    }
    if (threadIdx.x == 0) {
        binstart[NB] = N_EDGES;
        rowstart[N_NODES] = N_EDGES;  // sentinel for gather
    }
}

// chunked scatter into bin-contiguous binbuf; one global atomic per (block,bin)
__global__ void k_binscatter(const int* __restrict__ ei, int* __restrict__ bincur,
                             unsigned* __restrict__ binbuf) {
    __shared__ int h[NB];
    __shared__ int base[NB];
    for (int i = threadIdx.x; i < NB; i += 256) h[i] = 0;
    __syncthreads();
    int b0 = blockIdx.x * CHUNK;
    int e1 = b0 + CHUNK; if (e1 > N_EDGES) e1 = N_EDGES;
    for (int e = b0 + threadIdx.x; e < e1; e += 256)
        atomicAdd(&h[ei[N_EDGES + e] >> BINSHIFT], 1);
    __syncthreads();
    for (int i = threadIdx.x; i < NB; i += 256) {
        int c = h[i];
        if (c) base[i] = atomicAdd(&bincur[i], c);
        h[i] = 0;
    }
    __syncthreads();
    for (int e = b0 + threadIdx.x; e < e1; e += 256) {
        int d = ei[N_EDGES + e];
        int s = ei[e];
        int b = d >> BINSHIFT;
        int p = base[b] + atomicAdd(&h[b], 1);
        binbuf[p] = (unsigned)s | ((unsigned)(d & (BINSZ - 1)) << 17);  // s<2^17
    }
}

// one block per bin: per-node count -> LDS scan -> rowstart/dinv -> fill csr
__global__ void k_binfill(const unsigned* __restrict__ binbuf, const int* __restrict__ binstart,
                          int* __restrict__ rowstart, float* __restrict__ dinv,
                          int* __restrict__ csr_src) {
    int b = blockIdx.x;
    int ebeg = binstart[b];
    int eend = binstart[b + 1];
    __shared__ int cnt[BINSZ];
    __shared__ int rloc[BINSZ];
    __shared__ int cur[BINSZ];
    __shared__ int tmp[BINSZ];
    cnt[threadIdx.x] = 0;
    __syncthreads();
    for (int e = ebeg + threadIdx.x; e < eend; e += 256)
        atomicAdd(&cnt[binbuf[e] >> 17], 1);
    __syncthreads();
    int c = cnt[threadIdx.x];
    tmp[threadIdx.x] = c;
    __syncthreads();
    for (int off = 1; off < 256; off <<= 1) {
        int t = (threadIdx.x >= (unsigned)off) ? tmp[threadIdx.x - off] : 0;
        __syncthreads();
        tmp[threadIdx.x] += t;
        __syncthreads();
    }
    rloc[threadIdx.x] = tmp[threadIdx.x] - c;  // exclusive within bin
    cur[threadIdx.x] = 0;
    int node = b * BINSZ + threadIdx.x;
    if (node < N_NODES) {
        rowstart[node] = ebeg + rloc[threadIdx.x];
        dinv[node] = rsqrtf((float)c + 1.0f);  // +1 self-loop
    }
    __syncthreads();
    for (int e = ebeg + threadIdx.x; e < eend; e += 256) {
        unsigned v = binbuf[e];
        int dl = v >> 17;
        int s = (int)(v & 0x1FFFFu);
        int p = ebeg + rloc[dl] + atomicAdd(&cur[dl], 1);
        csr_src[p] = s;
    }
}

// ---------------- dense transforms ----------------
__global__ void k_xw1(const float* __restrict__ x, const float* __restrict__ W1,
                      float* __restrict__ xw) {
    int t = blockIdx.x * blockDim.x + threadIdx.x;
    if (t >= N_NODES * HID) return;
    int node = t >> 5;
    int j = t & 31;
    float acc = 0.0f;
#pragma unroll
    for (int k = 0; k < IN_DIM; ++k)
        acc += x[node * IN_DIM + k] * W1[k * HID + j];
    xw[t] = acc;
}

__global__ void k_xw2(const float* __restrict__ h, const float* __restrict__ W2,
                      float* __restrict__ xw) {
    int t = blockIdx.x * blockDim.x + threadIdx.x;
    int node = t >> 5;
    int j = t & 31;
    __shared__ float sW[HID * HID];
    for (int i = threadIdx.x; i < HID * HID; i += blockDim.x) sW[i] = W2[i];
    __syncthreads();
    if (t >= N_NODES * HID) return;
    float acc = 0.0f;
#pragma unroll
    for (int k = 0; k < HID; ++k)
        acc += h[node * HID + k] * sW[k * HID + j];
    xw[t] = acc;
}

// ---------------- CSR gather ----------------
__global__ __launch_bounds__(256) void k_gather(const int* __restrict__ rowstart,
                                                const int* __restrict__ csr_src,
                                                const float* __restrict__ dinv,
                                                const float* __restrict__ xw,
                                                const float* __restrict__ bias,
                                                float* __restrict__ outb, int do_relu) {
    int node = blockIdx.x * 8 + (threadIdx.x >> 5);
    int j = threadIdx.x & 31;
    if (node >= N_NODES) return;
    int beg = rowstart[node];
    int end = rowstart[node + 1];
    float acc = 0.0f;
    int e = beg;
    for (; e + 4 <= end; e += 4) {
        int s0 = csr_src[e], s1 = csr_src[e + 1], s2 = csr_src[e + 2], s3 = csr_src[e + 3];
        float d0 = dinv[s0], d1 = dinv[s1], d2 = dinv[s2], d3 = dinv[s3];
        float x0 = xw[s0 * HID + j], x1 = xw[s1 * HID + j];
        float x2 = xw[s2 * HID + j], x3 = xw[s3 * HID + j];
        acc += d0 * x0 + d1 * x1 + d2 * x2 + d3 * x3;
    }
    for (; e < end; ++e) {
        int s = csr_src[e];
        acc += dinv[s] * xw[s * HID + j];
    }
    float dd = dinv[node];
    float v = dd * acc + dd * dd * xw[node * HID + j];
    if (do_relu) {
        v += bias[j];
        v = v > 0.0f ? v : 0.0f;
    }
    outb[node * HID + j] = v;
}

// ---------------- output MLP ----------------
__global__ void k_mlp(const float* __restrict__ agg2, const float* __restrict__ b2,
                      const float* __restrict__ Wo1, const float* __restrict__ bo1,
                      const float* __restrict__ Wo2, const float* __restrict__ bo2,
                      float* __restrict__ out) {
    int node = blockIdx.x * blockDim.x + threadIdx.x;
    __shared__ float sW1[HID * HID2];
    __shared__ float sW2[HID2];
    __shared__ float sb1[HID2];
    for (int i = threadIdx.x; i < HID * HID2; i += blockDim.x) sW1[i] = Wo1[i];
    if (threadIdx.x < HID2) {
        sW2[threadIdx.x] = Wo2[threadIdx.x];
        sb1[threadIdx.x] = bo1[threadIdx.x];
    }
    __syncthreads();
    if (node >= N_NODES) return;
    float h[HID];
#pragma unroll
    for (int k = 0; k < HID; ++k) {
        float v = agg2[node * HID + k] + b2[k];
        h[k] = v > 0.0f ? v : 0.0f;
    }
    float o = bo2[0];
#pragma unroll
    for (int j = 0; j < HID2; ++j) {
        float a = sb1[j];
#pragma unroll
        for (int k = 0; k < HID; ++k) a += h[k] * sW1[k * HID2 + j];
        a = a > 0.0f ? a : (expf(a) - 1.0f);  // elu alpha=1
        o += a * sW2[j];
    }
    out[node] = o;
}

extern "C" void kernel_launch(void* const* d_in, const int* in_sizes, int n_in,
                              void* d_out, int out_size, void* d_ws, size_t ws_size,
                              hipStream_t stream) {
    const float* x   = (const float*)d_in[0];
    const int*   ei  = (const int*)d_in[1];
    const float* W1  = (const float*)d_in[3];
    const float* b1  = (const float*)d_in[4];
    const float* W2  = (const float*)d_in[5];
    const float* b2  = (const float*)d_in[6];
    const float* Wo1 = (const float*)d_in[7];
    const float* bo1 = (const float*)d_in[8];
    const float* Wo2 = (const float*)d_in[9];
    const float* bo2 = (const float*)d_in[10];
    float* out = (float*)d_out;

    // ws layout (4B units):
    // bincnt[512] | binstart[512] | bincur[512] | rowstart[SCHUNK] | dinv[SCHUNK]
    // | csr_src[E] | A[N*HID] | B[N*HID];  binbuf aliases A (dead until xw1)
    int*   bincnt   = (int*)d_ws;
    int*   binstart = bincnt + 512;
    int*   bincur   = binstart + 512;
    int*   rowstart = bincur + 512;
    float* dinv     = (float*)(rowstart + SCHUNK);
    int*   csr_src  = (int*)(dinv + SCHUNK);
    float* A        = (float*)(csr_src + N_EDGES);
    float* B        = A + (size_t)N_NODES * HID;
    unsigned* binbuf = (unsigned*)A;

    const int BT = 256;
    int gN   = (N_NODES + BT - 1) / BT;             // 391
    int gNH  = (N_NODES * HID + BT - 1) / BT;       // 12500
    int gC   = (N_EDGES + CHUNK - 1) / CHUNK;       // 391
    int gG   = (N_NODES + 7) / 8;                   // 12500

    // binned CSR build (rowstart, dinv, csr_src)
    k_zero_bins <<<1, 512, 0, stream>>>(bincnt);
    k_hist      <<<gC, BT, 0, stream>>>(ei, bincnt);
    k_scan_bins <<<1, 512, 0, stream>>>(bincnt, binstart, bincur, rowstart);
    k_binscatter<<<gC, BT, 0, stream>>>(ei, bincur, binbuf);
    k_binfill   <<<NB, BT, 0, stream>>>(binbuf, binstart, rowstart, dinv, csr_src);

    // layer 1: A = x@W1 ; B = gather(A) + bias + relu
    k_xw1<<<gNH, BT, 0, stream>>>(x, W1, A);
    k_gather<<<gG, BT, 0, stream>>>(rowstart, csr_src, dinv, A, b1, B, 1);

    // layer 2: A = B@W2 ; B = gather(A)  (bias+relu fused into mlp)
    k_xw2<<<gNH, BT, 0, stream>>>(B, W2, A);
    k_gather<<<gG, BT, 0, stream>>>(rowstart, csr_src, dinv, A, b1, B, 0);

    // head
    k_mlp<<<gN, BT, 0, stream>>>(B, b2, Wo1, bo1, Wo2, bo2, out);
}

// Round 4
// 324.181 us; speedup vs baseline: 3.1957x; 1.1220x over previous
//
#include <hip/hip_runtime.h>
#include <hip/hip_fp16.h>
#include <math.h>

#define N_NODES 100000
#define N_EDGES 3200000
#define IN_DIM 11
#define HID 32
#define HID2 16
#define SCHUNK 100352   // per-array stride in ws (multiple of 128)
#define BINSHIFT 8
#define BINSZ 256
#define NB 391          // ceil(100000/256)
#define CHUNK 8192      // edges per block in hist/scatter (391 blocks)

// ---------------- binned CSR build ----------------
// per-block LDS histogram of dst bins
__global__ void k_hist(const int* __restrict__ ei, int* __restrict__ bincnt) {
    __shared__ int h[NB];
    for (int i = threadIdx.x; i < NB; i += 256) h[i] = 0;
    __syncthreads();
    int b0 = blockIdx.x * CHUNK;
    int e1 = b0 + CHUNK; if (e1 > N_EDGES) e1 = N_EDGES;
    for (int e = b0 + threadIdx.x; e < e1; e += 256)
        atomicAdd(&h[ei[N_EDGES + e] >> BINSHIFT], 1);
    __syncthreads();
    for (int i = threadIdx.x; i < NB; i += 256)
        if (h[i]) atomicAdd(&bincnt[i], h[i]);
}

// exclusive scan of 391 bin counts (single block)
__global__ void k_scan_bins(const int* __restrict__ bincnt, int* __restrict__ binstart,
                            int* __restrict__ bincur, int* __restrict__ rowstart) {
    __shared__ int tmp[512];
    int v = (threadIdx.x < NB) ? bincnt[threadIdx.x] : 0;
    tmp[threadIdx.x] = v;
    __syncthreads();
    for (int off = 1; off < 512; off <<= 1) {
        int t = (threadIdx.x >= (unsigned)off) ? tmp[threadIdx.x - off] : 0;
        __syncthreads();
        tmp[threadIdx.x] += t;
        __syncthreads();
    }
    if (threadIdx.x < NB) {
        int ex = tmp[threadIdx.x] - v;
        binstart[threadIdx.x] = ex;
        bincur[threadIdx.x] = ex;
    }
    if (threadIdx.x == 0) {
        binstart[NB] = N_EDGES;
        rowstart[N_NODES] = N_EDGES;  // sentinel for gather
    }
}

// chunked scatter into bin-contiguous binbuf; one global atomic per (block,bin)
__global__ void k_binscatter(const int* __restrict__ ei, int* __restrict__ bincur,
                             unsigned* __restrict__ binbuf) {
    __shared__ int h[NB];
    __shared__ int base[NB];
    for (int i = threadIdx.x; i < NB; i += 256) h[i] = 0;
    __syncthreads();
    int b0 = blockIdx.x * CHUNK;
    int e1 = b0 + CHUNK; if (e1 > N_EDGES) e1 = N_EDGES;
    for (int e = b0 + threadIdx.x; e < e1; e += 256)
        atomicAdd(&h[ei[N_EDGES + e] >> BINSHIFT], 1);
    __syncthreads();
    for (int i = threadIdx.x; i < NB; i += 256) {
        int c = h[i];
        if (c) base[i] = atomicAdd(&bincur[i], c);
        h[i] = 0;
    }
    __syncthreads();
    for (int e = b0 + threadIdx.x; e < e1; e += 256) {
        int d = ei[N_EDGES + e];
        int s = ei[e];
        int b = d >> BINSHIFT;
        int p = base[b] + atomicAdd(&h[b], 1);
        binbuf[p] = (unsigned)s | ((unsigned)(d & (BINSZ - 1)) << 17);  // s<2^17
    }
}

// one block per bin: per-node count -> LDS scan -> rowstart/dinv -> fill csr
__global__ void k_binfill(const unsigned* __restrict__ binbuf, const int* __restrict__ binstart,
                          int* __restrict__ rowstart, float* __restrict__ dinv,
                          int* __restrict__ csr_src) {
    int b = blockIdx.x;
    int ebeg = binstart[b];
    int eend = binstart[b + 1];
    __shared__ int cnt[BINSZ];
    __shared__ int rloc[BINSZ];
    __shared__ int cur[BINSZ];
    __shared__ int tmp[BINSZ];
    cnt[threadIdx.x] = 0;
    __syncthreads();
    for (int e = ebeg + threadIdx.x; e < eend; e += 256)
        atomicAdd(&cnt[binbuf[e] >> 17], 1);
    __syncthreads();
    int c = cnt[threadIdx.x];
    tmp[threadIdx.x] = c;
    __syncthreads();
    for (int off = 1; off < 256; off <<= 1) {
        int t = (threadIdx.x >= (unsigned)off) ? tmp[threadIdx.x - off] : 0;
        __syncthreads();
        tmp[threadIdx.x] += t;
        __syncthreads();
    }
    rloc[threadIdx.x] = tmp[threadIdx.x] - c;  // exclusive within bin
    cur[threadIdx.x] = 0;
    int node = b * BINSZ + threadIdx.x;
    if (node < N_NODES) {
        rowstart[node] = ebeg + rloc[threadIdx.x];
        dinv[node] = rsqrtf((float)c + 1.0f);  // +1 self-loop
    }
    __syncthreads();
    for (int e = ebeg + threadIdx.x; e < eend; e += 256) {
        unsigned v = binbuf[e];
        int dl = v >> 17;
        int s = (int)(v & 0x1FFFFu);
        int p = ebeg + rloc[dl] + atomicAdd(&cur[dl], 1);
        csr_src[p] = s;
    }
}

// ---------------- dense transforms (write dinv-scaled fp16) ----------------
__global__ void k_xw1(const float* __restrict__ x, const float* __restrict__ W1,
                      const float* __restrict__ dinv, __half* __restrict__ xwh) {
    int t = blockIdx.x * blockDim.x + threadIdx.x;
    int node = t >> 5;
    int j = t & 31;
    __shared__ float sW[IN_DIM * HID];
    __shared__ float sx[8 * IN_DIM];
    for (int i = threadIdx.x; i < IN_DIM * HID; i += 256) sW[i] = W1[i];
    int base = blockIdx.x * 8;  // 8 nodes per block
    if (threadIdx.x < 8 * IN_DIM) sx[threadIdx.x] = x[base * IN_DIM + threadIdx.x];
    __syncthreads();
    int ln = node - base;
    float acc = 0.0f;
#pragma unroll
    for (int k = 0; k < IN_DIM; ++k)
        acc += sx[ln * IN_DIM + k] * sW[k * HID + j];
    xwh[t] = __float2half(dinv[node] * acc);
}

__global__ void k_xw2(const float* __restrict__ h, const float* __restrict__ W2,
                      const float* __restrict__ dinv, __half* __restrict__ xwh) {
    int t = blockIdx.x * blockDim.x + threadIdx.x;
    int node = t >> 5;
    int j = t & 31;
    __shared__ float sW[HID * HID];
    for (int i = threadIdx.x; i < HID * HID; i += 256) sW[i] = W2[i];
    __syncthreads();
    float acc = 0.0f;
#pragma unroll
    for (int k = 0; k < HID; ++k)
        acc += h[node * HID + k] * sW[k * HID + j];
    xwh[t] = __float2half(dinv[node] * acc);
}

// ---------------- CSR gather (fp16 pre-scaled rows, fp32 accumulate) ----------------
// 32 lanes per node, lane j = feature j.
// out = dinv[d] * ( sum_e XWH[src_e][j] + XWH[d][j] )   [+ bias, relu]
__global__ __launch_bounds__(256) void k_gather(const int* __restrict__ rowstart,
                                                const int* __restrict__ csr_src,
                                                const float* __restrict__ dinv,
                                                const __half* __restrict__ xwh,
                                                const float* __restrict__ bias,
                                                float* __restrict__ outb, int do_relu) {
    int node = blockIdx.x * 8 + (threadIdx.x >> 5);
    int j = threadIdx.x & 31;
    if (node >= N_NODES) return;
    int beg = rowstart[node];
    int end = rowstart[node + 1];
    float acc = 0.0f;
    int e = beg;
    for (; e + 8 <= end; e += 8) {
        int s0 = csr_src[e],     s1 = csr_src[e + 1], s2 = csr_src[e + 2], s3 = csr_src[e + 3];
        int s4 = csr_src[e + 4], s5 = csr_src[e + 5], s6 = csr_src[e + 6], s7 = csr_src[e + 7];
        float x0 = __half2float(xwh[s0 * HID + j]);
        float x1 = __half2float(xwh[s1 * HID + j]);
        float x2 = __half2float(xwh[s2 * HID + j]);
        float x3 = __half2float(xwh[s3 * HID + j]);
        float x4 = __half2float(xwh[s4 * HID + j]);
        float x5 = __half2float(xwh[s5 * HID + j]);
        float x6 = __half2float(xwh[s6 * HID + j]);
        float x7 = __half2float(xwh[s7 * HID + j]);
        acc += ((x0 + x1) + (x2 + x3)) + ((x4 + x5) + (x6 + x7));
    }
    for (; e + 2 <= end; e += 2) {
        int s0 = csr_src[e], s1 = csr_src[e + 1];
        acc += __half2float(xwh[s0 * HID + j]) + __half2float(xwh[s1 * HID + j]);
    }
    for (; e < end; ++e)
        acc += __half2float(xwh[csr_src[e] * HID + j]);
    float dd = dinv[node];
    float v = dd * (acc + __half2float(xwh[node * HID + j]));
    if (do_relu) {
        v += bias[j];
        v = v > 0.0f ? v : 0.0f;
    }
    outb[node * HID + j] = v;
}

// ---------------- output MLP ----------------
__global__ void k_mlp(const float* __restrict__ agg2, const float* __restrict__ b2,
                      const float* __restrict__ Wo1, const float* __restrict__ bo1,
                      const float* __restrict__ Wo2, const float* __restrict__ bo2,
                      float* __restrict__ out) {
    int node = blockIdx.x * blockDim.x + threadIdx.x;
    __shared__ float sW1[HID * HID2];
    __shared__ float sW2[HID2];
    __shared__ float sb1[HID2];
    for (int i = threadIdx.x; i < HID * HID2; i += blockDim.x) sW1[i] = Wo1[i];
    if (threadIdx.x < HID2) {
        sW2[threadIdx.x] = Wo2[threadIdx.x];
        sb1[threadIdx.x] = bo1[threadIdx.x];
    }
    __syncthreads();
    if (node >= N_NODES) return;
    float h[HID];
#pragma unroll
    for (int k = 0; k < HID; ++k) {
        float v = agg2[node * HID + k] + b2[k];
        h[k] = v > 0.0f ? v : 0.0f;
    }
    float o = bo2[0];
#pragma unroll
    for (int j = 0; j < HID2; ++j) {
        float a = sb1[j];
#pragma unroll
        for (int k = 0; k < HID; ++k) a += h[k] * sW1[k * HID2 + j];
        a = a > 0.0f ? a : (expf(a) - 1.0f);  // elu alpha=1
        o += a * sW2[j];
    }
    out[node] = o;
}

extern "C" void kernel_launch(void* const* d_in, const int* in_sizes, int n_in,
                              void* d_out, int out_size, void* d_ws, size_t ws_size,
                              hipStream_t stream) {
    const float* x   = (const float*)d_in[0];
    const int*   ei  = (const int*)d_in[1];
    const float* W1  = (const float*)d_in[3];
    const float* b1  = (const float*)d_in[4];
    const float* W2  = (const float*)d_in[5];
    const float* b2  = (const float*)d_in[6];
    const float* Wo1 = (const float*)d_in[7];
    const float* bo1 = (const float*)d_in[8];
    const float* Wo2 = (const float*)d_in[9];
    const float* bo2 = (const float*)d_in[10];
    float* out = (float*)d_out;

    // ws layout (4B units):
    // bincnt[512] | binstart[512] | bincur[512] | rowstart[SCHUNK] | dinv[SCHUNK]
    // | csr_src[E] | H[N*HID fp32] | XWH[N*HID fp16 = N*HID/2 dwords]
    // binbuf (E u32) aliases H (dead during CSR build)
    int*   bincnt   = (int*)d_ws;
    int*   binstart = bincnt + 512;
    int*   bincur   = binstart + 512;
    int*   rowstart = bincur + 512;
    float* dinv     = (float*)(rowstart + SCHUNK);
    int*   csr_src  = (int*)(dinv + SCHUNK);
    float* H        = (float*)(csr_src + N_EDGES);
    __half* XWH     = (__half*)(H + (size_t)N_NODES * HID);
    unsigned* binbuf = (unsigned*)H;

    const int BT = 256;
    int gN   = (N_NODES + BT - 1) / BT;             // 391
    int gNH  = (N_NODES * HID + BT - 1) / BT;       // 12500
    int gC   = (N_EDGES + CHUNK - 1) / CHUNK;       // 391
    int gG   = (N_NODES + 7) / 8;                   // 12500

    // binned CSR build (rowstart, dinv, csr_src)
    hipMemsetAsync(bincnt, 0, NB * sizeof(int), stream);
    k_hist      <<<gC, BT, 0, stream>>>(ei, bincnt);
    k_scan_bins <<<1, 512, 0, stream>>>(bincnt, binstart, bincur, rowstart);
    k_binscatter<<<gC, BT, 0, stream>>>(ei, bincur, binbuf);
    k_binfill   <<<NB, BT, 0, stream>>>(binbuf, binstart, rowstart, dinv, csr_src);

    // layer 1: XWH = fp16(dinv .* (x@W1)) ; H = relu(dinv.*gather(XWH) + b1)
    k_xw1<<<gNH, BT, 0, stream>>>(x, W1, dinv, XWH);
    k_gather<<<gG, BT, 0, stream>>>(rowstart, csr_src, dinv, XWH, b1, H, 1);

    // layer 2: XWH = fp16(dinv .* (H@W2)) ; H = dinv.*gather(XWH)  (bias+relu in mlp)
    k_xw2<<<gNH, BT, 0, stream>>>(H, W2, dinv, XWH);
    k_gather<<<gG, BT, 0, stream>>>(rowstart, csr_src, dinv, XWH, b1, H, 0);

    // head
    k_mlp<<<gN, BT, 0, stream>>>(H, b2, Wo1, bo1, Wo2, bo2, out);
}